// Round 6
// baseline (89.024 us; speedup 1.0000x reference)
//
#include <hip/hip_runtime.h>

#define CHUNK 256
#define MM 50
#define KK 4
#define STATE 200       // MM*KK
#define ASTRIDE 51      // odd granule stride (conflict-spread for uint2 rows)
#define SUP 32          // chunks per super-chunk
#define NSMAX 26        // max super-chunks (G<=832)
#define QUAD 4          // chunks per block
#define GMAX 1024

// Cross-block state in .bss device globals (zeroed at load). Epoch-valued
// flags (DONE = ticket/NB + 1) keep graph replays correct with no resets.
// All cross-block traffic uses per-access agent-scope atomics (sc1 -> MALL,
// bypassing non-coherent per-XCD L2). NO agent fences (bulk wbl2/inv cost
// ~100us/dispatch -- round-1 post-mortem).
__device__ int      g_ticket;
__device__ unsigned g_flag[GMAX];
__device__ unsigned g_sflag[64];
__device__ float    g_chunkB[GMAX * STATE];
__device__ float    g_superB[64 * STATE];

__device__ __forceinline__ unsigned short f2bf(float x) {
  unsigned u = __float_as_uint(x);
  u += 0x7fffu + ((u >> 16) & 1u);   // round-to-nearest-even
  return (unsigned short)(u >> 16);
}
__device__ __forceinline__ float bflo(unsigned u) { return __uint_as_float(u << 16); }
__device__ __forceinline__ float bfhi(unsigned u) { return __uint_as_float(u & 0xffff0000u); }

__device__ __forceinline__ void st_agent(float* p, float v) {
  __hip_atomic_store(p, v, __ATOMIC_RELAXED, __HIP_MEMORY_SCOPE_AGENT);
}
__device__ __forceinline__ float ld_agent(const float* p) {
  return __hip_atomic_load(p, __ATOMIC_RELAXED, __HIP_MEMORY_SCOPE_AGENT);
}
__device__ __forceinline__ void spin_flag(unsigned* p, unsigned want) {
  while (__hip_atomic_load(p, __ATOMIC_RELAXED, __HIP_MEMORY_SCOPE_AGENT) != want)
    __builtin_amdgcn_s_sleep(2);
}

// Block b owns chunks 4b..4b+3 (1024 events). Chain identity:
// S_{g+1} = d_g * S_g + Bv_g  (t_ref of chunk g+1 == te of chunk g),
// so ONE cross-block gather (chunk 4b, anchored tref0) serves all 4 chunks.
__global__ __launch_bounds__(512) void hawkes_quad(
    const float* __restrict__ ti, const int* __restrict__ mi,
    const float* __restrict__ mu, const float* __restrict__ alpha,
    const float* __restrict__ gamma, float* __restrict__ out,
    int N, int G, int NB) {
  int tid = threadIdx.x;
  __shared__ int vid_s;
  __shared__ uint2 P[MM * ASTRIDE];              // bf16x4 {k0,k1 | k2,k3} of gamma_k*alpha
  __shared__ __align__(16) float4 Fj[4 * CHUNK]; // exp(+gk*(t_j - tref_ch)), slot-indexed
  __shared__ int   cj[4 * CHUNK];
  __shared__ __align__(16) float Q[32][STATE];   // 8 sub-chunk levels per chunk
  __shared__ float BvL[QUAD][STATE];             // per-chunk summaries (for the chain)
  __shared__ float Slds[QUAD][STATE];            // per-chunk inter-prefix state
  __shared__ __align__(16) float RQ[QUAD][MM * 20]; // R[ch][c] float4, row stride 5 granules
  __shared__ float teL[SUP];                     // end times of chunks g0c..g0c+31
  __shared__ float tlast[NSMAX];                 // end times of supers 0..sup-1
  __shared__ float red8[8];

  if (tid == 0) vid_s = atomicAdd(&g_ticket, 1);

  int b = blockIdx.x;
  int c0 = b * QUAD;               // first chunk
  int lQ = c0 * CHUNK;
  int nEx = min(QUAD, G - c0);     // existing chunks in this block (1..4)
  int sup = b >> 3;                // 8 blocks = 32 chunks = 1 super
  int g0c = sup * SUP;
  int nloc = c0 - g0c;             // predecessor chunks within super (<=28)

  float gk0 = gamma[0], gk1 = gamma[1], gk2 = gamma[2], gk3 = gamma[3];

  for (int i = tid; i < 32 * STATE; i += 512) ((float*)Q)[i] = 0.f;

  if (tid < SUP) {
    int c = g0c + tid;
    if (c < G) teL[tid] = ti[min(N, (c + 1) * CHUNK) - 1];
  } else if (tid >= 64 && tid < 64 + NSMAX) {
    int s = tid - 64;
    if (s < sup) tlast[s] = ti[min(N, (s + 1) * SUP * CHUNK) - 1];
  }

  float tref0 = ti[(b == 0) ? 0 : (lQ - 1)];

  // ---- stage all 1024 event slots (2 per thread); slot s <-> source j = lQ-1+s
  int   myc[2]; float4 myF[2]; bool vld[2]; float trefE[2];
  #pragma unroll
  for (int ev = 0; ev < 2; ++ev) {
    int slot = tid + 512 * ev;
    int ch = slot >> 8;
    int j = lQ - 1 + slot;
    int rch = min(N, lQ + (ch + 1) * CHUNK);
    int tri = (b == 0 && ch == 0) ? 0 : (lQ + ch * CHUNK - 1);
    trefE[ev] = ti[min(N - 1, tri)];
    bool v = (j >= 0) && (j <= rch - 2);
    int c = 0; float4 F = make_float4(0.f, 0.f, 0.f, 0.f);
    if (v) {
      c = mi[j];
      float tj = ti[j] - trefE[ev];
      F = make_float4(__expf(gk0 * tj), __expf(gk1 * tj),
                      __expf(gk2 * tj), __expf(gk3 * tj));
    }
    myc[ev] = c; myF[ev] = F; vld[ev] = v;
    cj[slot] = c; Fj[slot] = F;
  }
  __syncthreads();   // B1: Q zeroed, staging done, teL/tlast/vid ready

  #pragma unroll
  for (int ev = 0; ev < 2; ++ev) {
    if (vld[ev]) {
      int slot = tid + 512 * ev;
      float* q = &Q[slot >> 5][myc[ev] * KK];
      atomicAdd(q + 0, myF[ev].x); atomicAdd(q + 1, myF[ev].y);
      atomicAdd(q + 2, myF[ev].z); atomicAdd(q + 3, myF[ev].w);
    }
  }
  __syncthreads();   // B2: all 32 bucket levels complete

  // ---- per-chunk summaries (4x200 items over 2 passes) + local prefixes
  #pragma unroll
  for (int half = 0; half < 2; ++half) {
    int it = tid + 512 * half;
    int ch = it >> 8, st = it & 255;
    if (st < STATE && ch < nEx) {
      float gkc = (st & 2) ? ((st & 1) ? gk3 : gk2) : ((st & 1) ? gk1 : gk0);
      float trefc = (ch == 0) ? tref0 : teL[nloc + ch - 1];
      float d = __expf(-gkc * (teL[nloc + ch] - trefc));
      float tot = 0.f;
      #pragma unroll
      for (int q = 0; q < 8; ++q) tot += Q[8 * ch + q][st];
      float Bv = d * tot;
      st_agent(&g_chunkB[(size_t)(c0 + ch) * STATE + st], Bv);
      BvL[ch][st] = Bv;
      float run = 0.f;
      #pragma unroll
      for (int q = 0; q < 8; ++q) {
        float tq = Q[8 * ch + q][st];
        Q[8 * ch + q][st] = run;
        run += tq;
      }
    }
  }
  if (b == 0 && tid == 0) st_agent(out, 0.f);
  __syncthreads();   // B3: chunkB stores drained per-wave at barrier
  unsigned DONE = (unsigned)(vid_s / NB) + 1u;
  if (tid == 0) {
    asm volatile("s_waitcnt vmcnt(0)" ::: "memory");
    for (int ch = 0; ch < nEx; ++ch)
      __hip_atomic_store(&g_flag[c0 + ch], DONE, __ATOMIC_RELAXED, __HIP_MEMORY_SCOPE_AGENT);
  }

  // ---- P staging + finals prefetch (off the flag critical path)
  for (int idx = tid; idx < MM * MM; idx += 512) {
    int c = idx / MM, cp = idx - c * MM;
    float a0 = gk0 * alpha[idx];
    float a1 = gk1 * alpha[2500 + idx];
    float a2 = gk2 * alpha[5000 + idx];
    float a3 = gk3 * alpha[7500 + idx];
    P[c * ASTRIDE + cp] =
        make_uint2((unsigned)f2bf(a0) | ((unsigned)f2bf(a1) << 16),
                   (unsigned)f2bf(a2) | ((unsigned)f2bf(a3) << 16));
  }
  int cn[2]; float tnv[2], muv[2]; bool en[2];
  #pragma unroll
  for (int ev = 0; ev < 2; ++ev) {
    int n = lQ + tid + 512 * ev;
    en[ev] = (n < N);
    cn[ev] = en[ev] ? mi[n] : 0;
    tnv[ev] = en[ev] ? (ti[n] - trefE[ev]) : 0.f;
    muv[ev] = en[ev] ? mu[n] : 0.f;
  }

  bool closer = ((b & 7) == 7 && nEx == QUAD) || (b == NB - 1);
  float gkc2 = (tid & 2) ? ((tid & 1) ? gk3 : gk2) : ((tid & 1) ? gk1 : gk0);
  float S0 = 0.f;

  // ---- closers: early spin + intra gather + chain -> superB publish
  if (closer) {
    if (tid < nloc) spin_flag(&g_flag[g0c + tid], DONE);
    __syncthreads();
    if (tid < STATE) {
      #pragma unroll 14
      for (int u = 0; u < nloc; ++u)
        S0 += __expf(-gkc2 * (tref0 - teL[u])) * ld_agent(&g_chunkB[(size_t)(g0c + u) * STATE + tid]);
      float s = S0;   // intra-super only: chain through own chunks
      for (int ch = 0; ch < nEx; ++ch) {
        float trefc = (ch == 0) ? tref0 : teL[nloc + ch - 1];
        float d = __expf(-gkc2 * (teL[nloc + ch] - trefc));
        s = d * s + BvL[ch][tid];
      }
      st_agent(&g_superB[(size_t)sup * STATE + tid], s);
    }
    __syncthreads();
    if (tid == 0) {
      asm volatile("s_waitcnt vmcnt(0)" ::: "memory");
      __hip_atomic_store(&g_sflag[sup], DONE, __ATOMIC_RELAXED, __HIP_MEMORY_SCOPE_AGENT);
    }
  }
  __syncthreads();   // B4: P staged; contraction may read it

  // ---- contraction: 2 events/thread, overlaps the grid-wide flag latency
  float4 acc[2];
  #pragma unroll
  for (int ev = 0; ev < 2; ++ev) {
    int slot = tid + 512 * ev;
    float4 a = make_float4(0.f, 0.f, 0.f, 0.f);
    if (en[ev]) {
      int rowb = cn[ev] * ASTRIDE;
      const float4* wb = (const float4*)&Q[slot >> 5][0];
      if ((slot & 255) >= 32) {   // sub-chunk 0 of each chunk has wb == 0
        #pragma unroll 10
        for (int m = 0; m < MM; ++m) {
          uint2 p = P[rowb + m];
          float4 w = wb[m];
          a.x += bflo(p.x) * w.x; a.y += bfhi(p.x) * w.y;
          a.z += bflo(p.y) * w.z; a.w += bfhi(p.y) * w.w;
        }
      }
      int base = slot & ~31;
      #pragma unroll 4
      for (int s = base; s <= slot; ++s) {
        uint2 p = P[rowb + cj[s]];
        float4 f = Fj[s];
        a.x += bflo(p.x) * f.x; a.y += bfhi(p.x) * f.y;
        a.z += bflo(p.y) * f.z; a.w += bfhi(p.y) * f.w;
      }
    }
    acc[ev] = a;
  }

  // ---- tail: gather S0 (flags long up), add supers, chain all 4 chunks
  if (!closer) {
    if (tid < nloc) spin_flag(&g_flag[g0c + tid], DONE);
    __syncthreads();
    if (tid < STATE) {
      #pragma unroll 14
      for (int u = 0; u < nloc; ++u)
        S0 += __expf(-gkc2 * (tref0 - teL[u])) * ld_agent(&g_chunkB[(size_t)(g0c + u) * STATE + tid]);
    }
  }
  if (tid < sup) spin_flag(&g_sflag[tid], DONE);
  __syncthreads();
  if (tid < STATE) {
    #pragma unroll 12
    for (int s = 0; s < sup; ++s)
      S0 += __expf(-gkc2 * (tref0 - tlast[s])) * ld_agent(&g_superB[(size_t)s * STATE + tid]);
    float s = S0;
    #pragma unroll
    for (int ch = 0; ch < QUAD; ++ch) {
      Slds[ch][tid] = s;
      float trefc = (ch == 0) ? tref0 : teL[nloc + ch - 1];
      float d = __expf(-gkc2 * (teL[nloc + ch] - trefc));
      s = d * s + BvL[ch][tid];
    }
  }
  __syncthreads();

  // ---- matvecs: R[ch][c][k] = sum_m P[c][m][k] * Slds[ch][m*4+k]
  #pragma unroll
  for (int half = 0; half < 2; ++half) {
    int it = tid + 512 * half;
    int ch = it >> 8, st = it & 255;
    if (st < STATE && ch < nEx) {
      int c = st >> 2, k = st & 3;
      float rv = 0.f;
      #pragma unroll 10
      for (int m = 0; m < MM; ++m) {
        uint2 p = P[c * ASTRIDE + m];
        unsigned w = (k & 2) ? p.y : p.x;
        float pv = (k & 1) ? bfhi(w) : bflo(w);
        rv += pv * Slds[ch][m * KK + k];
      }
      RQ[ch][c * 20 + k] = rv;
    }
  }
  __syncthreads();

  // ---- finalize both events, log-sum reduce
  float local = 0.f;
  #pragma unroll
  for (int ev = 0; ev < 2; ++ev) {
    if (en[ev]) {
      int ch = (tid + 512 * ev) >> 8;
      float4 rv = *(const float4*)&RQ[ch][cn[ev] * 20];
      float lam = muv[ev]
                + __expf(-gk0 * tnv[ev]) * (acc[ev].x + rv.x)
                + __expf(-gk1 * tnv[ev]) * (acc[ev].y + rv.y)
                + __expf(-gk2 * tnv[ev]) * (acc[ev].z + rv.z)
                + __expf(-gk3 * tnv[ev]) * (acc[ev].w + rv.w);
      local += __logf(lam);
    }
  }
  #pragma unroll
  for (int off = 32; off > 0; off >>= 1)
    local += __shfl_down(local, off, 64);
  if ((tid & 63) == 0) red8[tid >> 6] = local;
  __syncthreads();
  if (tid == 0) {
    float acc8 = 0.f;
    #pragma unroll
    for (int w = 0; w < 8; ++w) acc8 += red8[w];
    atomicAdd(out, acc8);
  }
}

extern "C" void kernel_launch(void* const* d_in, const int* in_sizes, int n_in,
                              void* d_out, int out_size, void* d_ws, size_t ws_size,
                              hipStream_t stream) {
  const float* ti    = (const float*)d_in[0];
  const int*   mi    = (const int*)d_in[1];
  const float* mu    = (const float*)d_in[2];
  const float* alpha = (const float*)d_in[3];
  const float* gamma = (const float*)d_in[4];
  float* out = (float*)d_out;
  int N = in_sizes[0];
  int G = (N + CHUNK - 1) / CHUNK;
  if (G > GMAX) return;   // problem is fixed at N=200000 (G=782); guard OOB
  int NB = (G + QUAD - 1) / QUAD;   // 196 blocks -> 1 per CU, all co-resident

  hawkes_quad<<<NB, 512, 0, stream>>>(ti, mi, mu, alpha, gamma, out, N, G, NB);
}

// Round 7
// 86.392 us; speedup vs baseline: 1.0305x; 1.0305x over previous
//
#include <hip/hip_runtime.h>

#define CHUNK 256
#define MM 50
#define KK 4
#define STATE 200       // MM*KK
#define ASTRIDE 51      // odd granule stride (conflict-spread for uint2 rows)
#define SUP 32          // chunks per super-chunk
#define NSMAX 26        // max super-chunks
#define GMAX 1024

// Dataflow protocol: publishers store epoch_s*(v+1) (v >= 0 always), readers
// poll until epoch_s*r >= 0.5. .bss zero-init = not-ready; sign flips per
// replay epoch so NO resets, NO flags, NO vmcnt drains, NO fences ever.
// All cross-block traffic via per-access agent-scope atomics (sc1 -> MALL).
__device__ int   g_ticket;
__device__ float g_chunkB[GMAX * STATE];
__device__ float g_superB[64 * STATE];

__device__ __forceinline__ unsigned short f2bf(float x) {
  unsigned u = __float_as_uint(x);
  u += 0x7fffu + ((u >> 16) & 1u);   // round-to-nearest-even
  return (unsigned short)(u >> 16);
}
__device__ __forceinline__ float bflo(unsigned u) { return __uint_as_float(u << 16); }
__device__ __forceinline__ float bfhi(unsigned u) { return __uint_as_float(u & 0xffff0000u); }

__device__ __forceinline__ void st_agent(float* p, float v) {
  __hip_atomic_store(p, v, __ATOMIC_RELAXED, __HIP_MEMORY_SCOPE_AGENT);
}
__device__ __forceinline__ float ld_agent(const float* p) {
  return __hip_atomic_load(p, __ATOMIC_RELAXED, __HIP_MEMORY_SCOPE_AGENT);
}

// Block b owns chunks 2b (A: slots 0..255) and 2b+1 (B: slots 256..511).
// Chain identity: S_B = dA*(S_A + totA)  (t_ref(B) == te(A)).
__global__ __launch_bounds__(512) void hawkes_df(
    const float* __restrict__ ti, const int* __restrict__ mi,
    const float* __restrict__ mu, const float* __restrict__ alpha,
    const float* __restrict__ gamma, float* __restrict__ out,
    int N, int G, int NB) {
  int tid = threadIdx.x;
  __shared__ int vid_s;
  __shared__ uint2 P[MM * ASTRIDE];              // bf16x4 {k0,k1 | k2,k3} of gamma_k*alpha
  __shared__ __align__(16) float4 Fj[512];       // exp(+gk*(t_j - tref_ch))
  __shared__ int   cj[512];
  __shared__ __align__(16) float Q[16][STATE];   // buckets -> W levels (S folded in)
  __shared__ float teL[SUP];                     // end times of chunks g0c..g0c+31
  __shared__ float tlast[NSMAX];                 // end times of supers 0..sup-1
  __shared__ float red8[8];

  if (tid == 0) vid_s = atomicAdd(&g_ticket, 1);

  int b = blockIdx.x;
  int c0 = 2 * b;
  int lQ = c0 * CHUNK;
  int sup = b >> 4;                 // 16 blocks = 32 chunks = 1 super
  int g0c = sup * SUP;
  int nloc = c0 - g0c;              // 0..30, even
  int ch = tid >> 8;                // 0 = chunk A, 1 = chunk B

  float gk0 = gamma[0], gk1 = gamma[1], gk2 = gamma[2], gk3 = gamma[3];

  for (int i = tid; i < 16 * STATE; i += 512) ((float*)Q)[i] = 0.f;
  if (tid < SUP) {
    int c = g0c + tid;
    if (c < G) teL[tid] = ti[min(N, (c + 1) * CHUNK) - 1];
  } else if (tid >= 64 && tid < 64 + NSMAX) {
    int s = tid - 64;
    if (s < sup) tlast[s] = ti[min(N, (s + 1) * SUP * CHUNK) - 1];
  }
  if (b == 0 && tid == 0) st_agent(out, 0.f);

  // single-load staging: this thread's event n; source j = n-1 via shuffle
  float tref_ch = ti[(b == 0 && ch == 0) ? 0 : (lQ + ch * CHUNK - 1)];
  int n = lQ + tid;
  bool has_n = (n < N);
  float ti_n = has_n ? ti[n] : 0.f;
  int   mi_n = has_n ? mi[n] : 0;
  float mu_n = has_n ? mu[n] : 0.f;
  int j = lQ - 1 + tid;
  float ti_j = __shfl_up(ti_n, 1, 64);
  int   mi_j = __shfl_up(mi_n, 1, 64);
  if ((tid & 63) == 0 && j >= 0) { ti_j = ti[j]; mi_j = mi[j]; }
  bool valid = (j >= 0) && has_n;
  int myc = valid ? mi_j : 0;
  float4 F = make_float4(0.f, 0.f, 0.f, 0.f);
  if (valid) {
    float tj = ti_j - tref_ch;
    F = make_float4(__expf(gk0 * tj), __expf(gk1 * tj),
                    __expf(gk2 * tj), __expf(gk3 * tj));
  }
  cj[tid] = myc;
  Fj[tid] = F;
  __syncthreads();   // B1: Q zeroed, events staged, teL/tlast/vid ready

  // buckets + P staging (loads overlap the LDS atomics)
  if (valid) {
    float* q = &Q[tid >> 5][myc * KK];
    atomicAdd(q + 0, F.x); atomicAdd(q + 1, F.y);
    atomicAdd(q + 2, F.z); atomicAdd(q + 3, F.w);
  }
  #pragma unroll
  for (int u = 0; u < 5; ++u) {
    int idx = tid + 512 * u;
    if (idx < MM * MM) {
      int c = idx / MM, cp = idx - c * MM;
      float a0 = gk0 * alpha[idx];
      float a1 = gk1 * alpha[2500 + idx];
      float a2 = gk2 * alpha[5000 + idx];
      float a3 = gk3 * alpha[7500 + idx];
      P[c * ASTRIDE + cp] =
          make_uint2((unsigned)f2bf(a0) | ((unsigned)f2bf(a1) << 16),
                     (unsigned)f2bf(a2) | ((unsigned)f2bf(a3) << 16));
    }
  }
  __syncthreads();   // B2: buckets + P complete

  float epoch_s = ((vid_s / NB) & 1) ? -1.f : 1.f;
  float gkc = (tid & 2) ? ((tid & 1) ? gk3 : gk2) : ((tid & 1) ? gk1 : gk0);
  float totA = 0.f, totB = 0.f, dA = 0.f, dB = 0.f;
  if (tid < STATE) {   // publish both chunk summaries IMMEDIATELY (fire & forget)
    #pragma unroll
    for (int q = 0; q < 8; ++q)  totA += Q[q][tid];
    #pragma unroll
    for (int q = 8; q < 16; ++q) totB += Q[q][tid];
    dA = __expf(-gkc * (teL[nloc] - tref_ch));              // tref_ch==tref0 here
    dB = __expf(-gkc * (teL[nloc + 1] - teL[nloc]));
    st_agent(&g_chunkB[(size_t)c0 * STATE + tid], epoch_s * (dA * totA + 1.f));
    st_agent(&g_chunkB[(size_t)(c0 + 1) * STATE + tid], epoch_s * (dB * totB + 1.f));
  }

  // pairwise contraction (needs no S): runs while publishes land grid-wide
  float4 acc = make_float4(0.f, 0.f, 0.f, 0.f);
  if (has_n) {
    int rowb = mi_n * ASTRIDE;
    int base = tid & ~31;
    #pragma unroll 4
    for (int s = base; s <= tid; ++s) {
      uint2 p = P[rowb + cj[s]];
      float4 f = Fj[s];
      acc.x += bflo(p.x) * f.x; acc.y += bfhi(p.x) * f.y;
      acc.z += bflo(p.y) * f.z; acc.w += bfhi(p.y) * f.w;
    }
  }

  // dataflow gathers (tid<200): batched issue-16 then poll stragglers
  bool closer = ((b & 15) == 15) || (b == NB - 1);
  float S = 0.f;
  if (tid < STATE) {
    // intra-super predecessors
    for (int u0 = 0; u0 < nloc; u0 += 16) {
      float r[16];
      #pragma unroll
      for (int u = 0; u < 16; ++u)
        r[u] = (u0 + u < nloc)
             ? ld_agent(&g_chunkB[(size_t)(g0c + u0 + u) * STATE + tid])
             : epoch_s;
      #pragma unroll
      for (int u = 0; u < 16; ++u) {
        if (u0 + u < nloc) {
          float v = r[u];
          while (epoch_s * v < 0.5f) {
            __builtin_amdgcn_s_sleep(1);
            v = ld_agent(&g_chunkB[(size_t)(g0c + u0 + u) * STATE + tid]);
          }
          S += __expf(-gkc * (tref_ch - teL[u0 + u])) * (epoch_s * v - 1.f);
        }
      }
    }
    if (closer) {   // publish super summary from intra info only (registers)
      float run2 = dA * (S + totA);
      run2 = dB * (run2 + totB);
      st_agent(&g_superB[(size_t)sup * STATE + tid], epoch_s * (run2 + 1.f));
    }
    // earlier supers
    for (int s0 = 0; s0 < sup; s0 += 16) {
      float r[16];
      #pragma unroll
      for (int u = 0; u < 16; ++u)
        r[u] = (s0 + u < sup)
             ? ld_agent(&g_superB[(size_t)(s0 + u) * STATE + tid])
             : epoch_s;
      #pragma unroll
      for (int u = 0; u < 16; ++u) {
        if (s0 + u < sup) {
          float v = r[u];
          while (epoch_s * v < 0.5f) {
            __builtin_amdgcn_s_sleep(1);
            v = ld_agent(&g_superB[(size_t)(s0 + u) * STATE + tid]);
          }
          S += __expf(-gkc * (tref_ch - tlast[s0 + u])) * (epoch_s * v - 1.f);
        }
      }
    }
    // W levels with S folded in: Q[q] <- running prefix (A then B chained)
    float run = S;
    #pragma unroll
    for (int q = 0; q < 8; ++q)  { float t = Q[q][tid]; Q[q][tid] = run; run += t; }
    run = dA * run;   // S_B = dA*(S_A + totA)
    #pragma unroll
    for (int q = 8; q < 16; ++q) { float t = Q[q][tid]; Q[q][tid] = run; run += t; }
  }
  __syncthreads();   // B3: W levels ready

  // prefix contraction over marks + finalize
  float local = 0.f;
  if (has_n) {
    int rowb = mi_n * ASTRIDE;
    const float4* wb = (const float4*)&Q[tid >> 5][0];
    #pragma unroll 10
    for (int m = 0; m < MM; ++m) {
      uint2 p = P[rowb + m];
      float4 w = wb[m];
      acc.x += bflo(p.x) * w.x; acc.y += bfhi(p.x) * w.y;
      acc.z += bflo(p.y) * w.z; acc.w += bfhi(p.y) * w.w;
    }
    float tn = ti_n - tref_ch;
    float lam = mu_n
              + __expf(-gk0 * tn) * acc.x + __expf(-gk1 * tn) * acc.y
              + __expf(-gk2 * tn) * acc.z + __expf(-gk3 * tn) * acc.w;
    local = __logf(lam);
  }
  #pragma unroll
  for (int off = 32; off > 0; off >>= 1)
    local += __shfl_down(local, off, 64);
  if ((tid & 63) == 0) red8[tid >> 6] = local;
  __syncthreads();
  if (tid == 0) {
    float acc8 = 0.f;
    #pragma unroll
    for (int w = 0; w < 8; ++w) acc8 += red8[w];
    atomicAdd(out, acc8);
  }
}

extern "C" void kernel_launch(void* const* d_in, const int* in_sizes, int n_in,
                              void* d_out, int out_size, void* d_ws, size_t ws_size,
                              hipStream_t stream) {
  const float* ti    = (const float*)d_in[0];
  const int*   mi    = (const int*)d_in[1];
  const float* mu    = (const float*)d_in[2];
  const float* alpha = (const float*)d_in[3];
  const float* gamma = (const float*)d_in[4];
  float* out = (float*)d_out;
  int N = in_sizes[0];
  int G = (N + CHUNK - 1) / CHUNK;
  if (G > GMAX) return;   // problem is fixed at N=200000 (G=782); guard OOB
  int NB = (G + 1) / 2;   // 391 blocks, 2 chunks each

  hawkes_df<<<NB, 512, 0, stream>>>(ti, mi, mu, alpha, gamma, out, N, G, NB);
}

// Round 8
// 85.857 us; speedup vs baseline: 1.0369x; 1.0062x over previous
//
#include <hip/hip_runtime.h>

#define CHUNK 256
#define MM 50
#define KK 4
#define STATE 200       // MM*KK
#define ASTRIDE 51      // odd WORD stride: bank = (19c+m) mod 32 -> all 32 banks
#define SUP 32          // chunks per super-chunk
#define NSMAX 26        // max super-chunks
#define GMAX 1024

// Dataflow protocol: publishers store epoch_s*(v+1) (v >= 0 always), readers
// poll until epoch_s*r >= 0.5. .bss zero-init = not-ready; sign flips per
// replay epoch so NO resets, NO flags, NO vmcnt drains, NO fences ever.
// All cross-block traffic via per-access agent-scope atomics (sc1 -> MALL).
__device__ int   g_ticket;
__device__ float g_chunkB[GMAX * STATE];
__device__ float g_superB[64 * STATE];

__device__ __forceinline__ unsigned short f2bf(float x) {
  unsigned u = __float_as_uint(x);
  u += 0x7fffu + ((u >> 16) & 1u);   // round-to-nearest-even
  return (unsigned short)(u >> 16);
}
__device__ __forceinline__ float bflo(unsigned u) { return __uint_as_float(u << 16); }
__device__ __forceinline__ float bfhi(unsigned u) { return __uint_as_float(u & 0xffff0000u); }

__device__ __forceinline__ void st_agent(float* p, float v) {
  __hip_atomic_store(p, v, __ATOMIC_RELAXED, __HIP_MEMORY_SCOPE_AGENT);
}
__device__ __forceinline__ float ld_agent(const float* p) {
  return __hip_atomic_load(p, __ATOMIC_RELAXED, __HIP_MEMORY_SCOPE_AGENT);
}

// Block b owns chunks 2b (A: slots 0..255) and 2b+1 (B: slots 256..511).
// Chain identity: S_B = dA*(S_A + totA)  (t_ref(B) == te(A)).
__global__ __launch_bounds__(512) void hawkes_df(
    const float* __restrict__ ti, const int* __restrict__ mi,
    const float* __restrict__ mu, const float* __restrict__ alpha,
    const float* __restrict__ gamma, float* __restrict__ out,
    int N, int G, int NB) {
  int tid = threadIdx.x;
  __shared__ int vid_s;
  __shared__ unsigned P0[MM * ASTRIDE];          // bf16x2 {k0,k1} of gamma_k*alpha
  __shared__ unsigned P1[MM * ASTRIDE];          // bf16x2 {k2,k3}  (b32 reads: ~2-way, free)
  __shared__ __align__(16) float4 Fj[512];       // exp(+gk*(t_j - tref_ch))
  __shared__ int   cj[512];
  __shared__ __align__(16) float Q[16][STATE];   // buckets -> W levels (S folded in)
  __shared__ float SB1[STATE];                   // group-B partial (intra gather)
  __shared__ float SB2[STATE];                   // group-B partial (super gather)
  __shared__ float teL[SUP];                     // end times of chunks g0c..g0c+31
  __shared__ float tlast[NSMAX];                 // end times of supers 0..sup-1
  __shared__ float red8[8];

  if (tid == 0) vid_s = atomicAdd(&g_ticket, 1);

  int b = blockIdx.x;
  int c0 = 2 * b;
  int lQ = c0 * CHUNK;
  int sup = b >> 4;                 // 16 blocks = 32 chunks = 1 super
  int g0c = sup * SUP;
  int nloc = c0 - g0c;              // 0..30, even
  int ch = tid >> 8;                // 0 = chunk A, 1 = chunk B

  float gk0 = gamma[0], gk1 = gamma[1], gk2 = gamma[2], gk3 = gamma[3];

  for (int i = tid; i < 16 * STATE; i += 512) ((float*)Q)[i] = 0.f;
  if (tid < SUP) {
    int c = g0c + tid;
    if (c < G) teL[tid] = ti[min(N, (c + 1) * CHUNK) - 1];
  } else if (tid >= 64 && tid < 64 + NSMAX) {
    int s = tid - 64;
    if (s < sup) tlast[s] = ti[min(N, (s + 1) * SUP * CHUNK) - 1];
  }
  if (b == 0 && tid == 0) st_agent(out, 0.f);

  // single-load staging: this thread's event n; source j = n-1 via shuffle
  float tref0 = ti[(b == 0) ? 0 : (lQ - 1)];
  float tref_ch = ch ? ti[min(N - 1, lQ + CHUNK - 1)] : tref0;
  int n = lQ + tid;
  bool has_n = (n < N);
  float ti_n = has_n ? ti[n] : 0.f;
  int   mi_n = has_n ? mi[n] : 0;
  float mu_n = has_n ? mu[n] : 0.f;
  int j = lQ - 1 + tid;
  float ti_j = __shfl_up(ti_n, 1, 64);
  int   mi_j = __shfl_up(mi_n, 1, 64);
  if ((tid & 63) == 0 && j >= 0) { ti_j = ti[j]; mi_j = mi[j]; }
  bool valid = (j >= 0) && has_n;
  int myc = valid ? mi_j : 0;
  float4 F = make_float4(0.f, 0.f, 0.f, 0.f);
  if (valid) {
    float tj = ti_j - tref_ch;
    F = make_float4(__expf(gk0 * tj), __expf(gk1 * tj),
                    __expf(gk2 * tj), __expf(gk3 * tj));
  }
  cj[tid] = myc;
  Fj[tid] = F;
  __syncthreads();   // B1: Q zeroed, events staged, teL/tlast/vid ready

  // buckets + P staging (loads overlap the LDS atomics)
  if (valid) {
    float* q = &Q[tid >> 5][myc * KK];
    atomicAdd(q + 0, F.x); atomicAdd(q + 1, F.y);
    atomicAdd(q + 2, F.z); atomicAdd(q + 3, F.w);
  }
  #pragma unroll
  for (int u = 0; u < 5; ++u) {
    int idx = tid + 512 * u;
    if (idx < MM * MM) {
      int c = idx / MM, cp = idx - c * MM;
      float a0 = gk0 * alpha[idx];
      float a1 = gk1 * alpha[2500 + idx];
      float a2 = gk2 * alpha[5000 + idx];
      float a3 = gk3 * alpha[7500 + idx];
      P0[c * ASTRIDE + cp] = (unsigned)f2bf(a0) | ((unsigned)f2bf(a1) << 16);
      P1[c * ASTRIDE + cp] = (unsigned)f2bf(a2) | ((unsigned)f2bf(a3) << 16);
    }
  }
  __syncthreads();   // B2: buckets + P complete

  float epoch_s = ((vid_s / NB) & 1) ? -1.f : 1.f;
  float gkc = (tid & 2) ? ((tid & 1) ? gk3 : gk2) : ((tid & 1) ? gk1 : gk0);
  float totA = 0.f, totB = 0.f, dA = 0.f, dB = 0.f;
  if (tid < STATE) {   // publish both chunk summaries IMMEDIATELY (fire & forget)
    #pragma unroll
    for (int q = 0; q < 8; ++q)  totA += Q[q][tid];
    #pragma unroll
    for (int q = 8; q < 16; ++q) totB += Q[q][tid];
    dA = __expf(-gkc * (teL[nloc] - tref0));
    dB = __expf(-gkc * (teL[nloc + 1] - teL[nloc]));
    st_agent(&g_chunkB[(size_t)c0 * STATE + tid], epoch_s * (dA * totA + 1.f));
    st_agent(&g_chunkB[(size_t)(c0 + 1) * STATE + tid], epoch_s * (dB * totB + 1.f));
  }

  // pairwise contraction (needs no S): runs while publishes land grid-wide
  float4 acc = make_float4(0.f, 0.f, 0.f, 0.f);
  if (has_n) {
    int rowb = mi_n * ASTRIDE;
    int base = tid & ~31;
    #pragma unroll 4
    for (int s = base; s <= tid; ++s) {
      unsigned p0 = P0[rowb + cj[s]];
      unsigned p1 = P1[rowb + cj[s]];
      float4 f = Fj[s];
      acc.x += bflo(p0) * f.x; acc.y += bfhi(p0) * f.y;
      acc.z += bflo(p1) * f.z; acc.w += bfhi(p1) * f.w;
    }
  }

  // ---- dataflow gathers, parity-split across two 200-thread groups
  bool closer = ((b & 15) == 15) || (b == NB - 1);
  bool grpA = (tid < STATE);
  bool grpB = (tid >= 256) && (tid < 256 + STATE);
  int st = grpB ? (tid - 256) : tid;   // state index per group
  float SA = 0.f;

  int cpar = nloc >> 1;   // nloc even: #even-u == #odd-u == nloc/2 (<=15)
  if (grpA && cpar) {     // even u
    float r[15];
    #pragma unroll
    for (int i = 0; i < 15; ++i)
      r[i] = (i < cpar) ? ld_agent(&g_chunkB[(size_t)(g0c + 2 * i) * STATE + st]) : epoch_s;
    #pragma unroll
    for (int i = 0; i < 15; ++i) if (i < cpar) {
      float v = r[i];
      while (epoch_s * v < 0.5f) {
        __builtin_amdgcn_s_sleep(1);
        v = ld_agent(&g_chunkB[(size_t)(g0c + 2 * i) * STATE + st]);
      }
      SA += __expf(-gkc * (tref0 - teL[2 * i])) * (epoch_s * v - 1.f);
    }
  }
  if (grpB) {             // odd u
    float PB = 0.f;
    if (cpar) {
      float r[15];
      #pragma unroll
      for (int i = 0; i < 15; ++i)
        r[i] = (i < cpar) ? ld_agent(&g_chunkB[(size_t)(g0c + 2 * i + 1) * STATE + st]) : epoch_s;
      #pragma unroll
      for (int i = 0; i < 15; ++i) if (i < cpar) {
        float v = r[i];
        while (epoch_s * v < 0.5f) {
          __builtin_amdgcn_s_sleep(1);
          v = ld_agent(&g_chunkB[(size_t)(g0c + 2 * i + 1) * STATE + st]);
        }
        PB += __expf(-gkc * (tref0 - teL[2 * i + 1])) * (epoch_s * v - 1.f);
      }
    }
    SB1[st] = PB;
  }

  if (closer) {
    __syncthreads();   // C1: SB1 ready (block-uniform branch: legal)
    if (grpA) {
      float Sin = SA + SB1[st];          // full intra sum anchored tref0
      float run2 = dA * (Sin + totA);
      run2 = dB * (run2 + totB);
      st_agent(&g_superB[(size_t)sup * STATE + st], epoch_s * (run2 + 1.f));
      SA = Sin;                          // SB1 now folded in: don't re-add
    }
  }

  int cse = (sup + 1) >> 1, cso = sup >> 1;   // even/odd super counts (<=13/12)
  if (grpA && cse) {
    float r[13];
    #pragma unroll
    for (int i = 0; i < 13; ++i)
      r[i] = (i < cse) ? ld_agent(&g_superB[(size_t)(2 * i) * STATE + st]) : epoch_s;
    #pragma unroll
    for (int i = 0; i < 13; ++i) if (i < cse) {
      float v = r[i];
      while (epoch_s * v < 0.5f) {
        __builtin_amdgcn_s_sleep(1);
        v = ld_agent(&g_superB[(size_t)(2 * i) * STATE + st]);
      }
      SA += __expf(-gkc * (tref0 - tlast[2 * i])) * (epoch_s * v - 1.f);
    }
  }
  if (grpB) {
    float PB2 = 0.f;
    if (cso) {
      float r[12];
      #pragma unroll
      for (int i = 0; i < 12; ++i)
        r[i] = (i < cso) ? ld_agent(&g_superB[(size_t)(2 * i + 1) * STATE + st]) : epoch_s;
      #pragma unroll
      for (int i = 0; i < 12; ++i) if (i < cso) {
        float v = r[i];
        while (epoch_s * v < 0.5f) {
          __builtin_amdgcn_s_sleep(1);
          v = ld_agent(&g_superB[(size_t)(2 * i + 1) * STATE + st]);
        }
        PB2 += __expf(-gkc * (tref0 - tlast[2 * i + 1])) * (epoch_s * v - 1.f);
      }
    }
    SB2[st] = PB2;
  }
  __syncthreads();   // C2: all partials ready

  if (grpA) {
    float S = SA + SB2[st] + (closer ? 0.f : SB1[st]);
    // W levels with S folded in: Q[q] <- running prefix (A then B chained)
    float run = S;
    #pragma unroll
    for (int q = 0; q < 8; ++q)  { float t = Q[q][st]; Q[q][st] = run; run += t; }
    run = dA * run;   // S_B = dA*(S_A + totA)
    #pragma unroll
    for (int q = 8; q < 16; ++q) { float t = Q[q][st]; Q[q][st] = run; run += t; }
  }
  __syncthreads();   // B3: W levels ready

  // prefix contraction over marks + finalize
  float local = 0.f;
  if (has_n) {
    int rowb = mi_n * ASTRIDE;
    const float4* wb = (const float4*)&Q[tid >> 5][0];
    #pragma unroll 10
    for (int m = 0; m < MM; ++m) {
      unsigned p0 = P0[rowb + m];
      unsigned p1 = P1[rowb + m];
      float4 w = wb[m];
      acc.x += bflo(p0) * w.x; acc.y += bfhi(p0) * w.y;
      acc.z += bflo(p1) * w.z; acc.w += bfhi(p1) * w.w;
    }
    float tn = ti_n - tref_ch;
    float lam = mu_n
              + __expf(-gk0 * tn) * acc.x + __expf(-gk1 * tn) * acc.y
              + __expf(-gk2 * tn) * acc.z + __expf(-gk3 * tn) * acc.w;
    local = __logf(lam);
  }
  #pragma unroll
  for (int off = 32; off > 0; off >>= 1)
    local += __shfl_down(local, off, 64);
  if ((tid & 63) == 0) red8[tid >> 6] = local;
  __syncthreads();
  if (tid == 0) {
    float acc8 = 0.f;
    #pragma unroll
    for (int w = 0; w < 8; ++w) acc8 += red8[w];
    atomicAdd(out, acc8);
  }
}

extern "C" void kernel_launch(void* const* d_in, const int* in_sizes, int n_in,
                              void* d_out, int out_size, void* d_ws, size_t ws_size,
                              hipStream_t stream) {
  const float* ti    = (const float*)d_in[0];
  const int*   mi    = (const int*)d_in[1];
  const float* mu    = (const float*)d_in[2];
  const float* alpha = (const float*)d_in[3];
  const float* gamma = (const float*)d_in[4];
  float* out = (float*)d_out;
  int N = in_sizes[0];
  int G = (N + CHUNK - 1) / CHUNK;
  if (G > GMAX) return;   // problem is fixed at N=200000 (G=782); guard OOB
  int NB = (G + 1) / 2;   // 391 blocks, 2 chunks each

  hawkes_df<<<NB, 512, 0, stream>>>(ti, mi, mu, alpha, gamma, out, N, G, NB);
}